// Round 1
// baseline (41.490 us; speedup 1.0000x reference)
//
#include <hip/hip_runtime.h>

// Pairlist: 1024 molecules x 100 atoms, all ordered pairs i != j within each
// molecule. Structure is static: 9900 pairs/molecule, 10,137,600 total.
//
// Output layout (all float32, concatenated flat in reference return order):
//   [0          , NP)        : pair_indices row 0 (i), as float
//   [NP         , 2*NP)      : pair_indices row 1 (j), as float
//   [2*NP       , 3*NP)      : d_ij
//   [3*NP       , 6*NP)      : r_ij (n_pairs, 3) row-major
//
// Pair ordering faithful to reference: i-major (global atom order), j ascending
// within i's molecule, skipping j == i.

#define N_MOL 1024
#define APM   100              // atoms per molecule
#define PPM   (APM * (APM-1))  // 9900 pairs per molecule
#define NP    (N_MOL * PPM)    // 10,137,600 total pairs

__global__ __launch_bounds__(256) void pairlist_kernel(
    const float* __restrict__ pos,   // (102400, 3)
    float* __restrict__ out)
{
    int p = blockIdx.x * blockDim.x + threadIdx.x;
    if (p >= NP) return;

    unsigned up = (unsigned)p;
    unsigned m  = up / (unsigned)PPM;          // molecule
    unsigned r  = up - m * (unsigned)PPM;
    unsigned il = r / 99u;                     // local i
    unsigned k  = r - il * 99u;                // pair slot within i's row
    unsigned jl = k + (k >= il ? 1u : 0u);     // local j (skip j == i)
    unsigned i  = m * (unsigned)APM + il;
    unsigned j  = m * (unsigned)APM + jl;

    // positions: tiny working set (1.2 KB per molecule, 1.2 MB total) -> cached
    float xi = pos[3u*i + 0u], yi = pos[3u*i + 1u], zi = pos[3u*i + 2u];
    float xj = pos[3u*j + 0u], yj = pos[3u*j + 1u], zj = pos[3u*j + 2u];

    float rx = xj - xi, ry = yj - yi, rz = zj - zi;
    float d  = sqrtf(rx*rx + ry*ry + rz*rz);

    out[p]          = (float)i;
    out[NP + p]     = (float)j;
    out[2*NP + p]   = d;

    float* rr = out + (size_t)3 * NP;
    size_t b = (size_t)3 * (size_t)p;
    rr[b + 0] = rx;
    rr[b + 1] = ry;
    rr[b + 2] = rz;
}

extern "C" void kernel_launch(void* const* d_in, const int* in_sizes, int n_in,
                              void* d_out, int out_size, void* d_ws, size_t ws_size,
                              hipStream_t stream) {
    const float* pos = (const float*)d_in[0];
    float* out = (float*)d_out;
    int nblocks = (NP + 255) / 256;
    pairlist_kernel<<<nblocks, 256, 0, stream>>>(pos, out);
}